// Round 1
// baseline (76.369 us; speedup 1.0000x reference)
//
#include <hip/hip_runtime.h>
#include <math.h>

#define N 4096
#define M 4095          // number of segments
#define EPSF 1e-9f
#define BLK 256
#define JT 64           // j's per block (j-chunk size)
#define INV_4PI 0.07957747154594767f

// Kernel A: precompute r1 (quaternion-normalized curve) and r2 (exact one-hot)
// into ws as SoA float arrays; zero the output accumulator.
__global__ __launch_bounds__(256) void precompute_kernel(
    const float* __restrict__ bytes, const int* __restrict__ idx,
    float* __restrict__ ws, float* __restrict__ out) {
  int i = blockIdx.x * blockDim.x + threadIdx.x;
  if (i == 0) out[0] = 0.0f;
  if (i < N) {
    float b = bytes[i];
    float theta = (b / 255.0f) * 6.28318530717958647692f;
    float s, c;
    sincosf(theta, &s, &c);
    float q1 = 0.5f * s, q2 = 0.3f * s, q3 = 0.2f * s;
    float n2 = c * c + q1 * q1 + q2 * q2 + q3 * q3 + EPSF;
    float inv = 1.0f / sqrtf(n2);
    ws[0 * N + i] = q1 * inv;
    ws[1 * N + i] = q2 * inv;
    ws[2 * N + i] = q3 * inv;
    // r2: normalize(eye(4)[idx])[1:4]. In fp32, 1.0 + 1e-9 == 1.0 exactly,
    // so the one-hot survives normalization unchanged.
    int id = idx[i];
    ws[3 * N + i] = (id == 1) ? 1.0f : 0.0f;
    ws[4 * N + i] = (id == 2) ? 1.0f : 0.0f;
    ws[5 * N + i] = (id == 3) ? 1.0f : 0.0f;
  }
}

// Kernel B: pairwise Gauss-linking sum.
// Grid: (16 i-tiles of 256) x (64 j-chunks of 64) = 1024 blocks.
// Each thread owns one i; j-chunk's dr2/m2 staged in LDS (broadcast reads).
__global__ __launch_bounds__(256) void gauss_pairs_kernel(
    const float* __restrict__ ws, float* __restrict__ out) {
  const float* r1x = ws + 0 * N;
  const float* r1y = ws + 1 * N;
  const float* r1z = ws + 2 * N;
  const float* r2x = ws + 3 * N;
  const float* r2y = ws + 4 * N;
  const float* r2z = ws + 5 * N;

  __shared__ float4 sA[JT];  // (dr2x, dr2y, dr2z, m2x)
  __shared__ float2 sB[JT];  // (m2y, m2z)
  __shared__ float wsum[BLK / 64];

  int tid = threadIdx.x;
  int i = blockIdx.x * BLK + tid;
  int jbase = blockIdx.y * JT;

  if (tid < JT) {
    int j = jbase + tid;
    float ax = r2x[j], ay = r2y[j], az = r2z[j];
    float bx, by, bz;
    if (j < M) {             // j+1 <= 4095 < N : safe
      bx = r2x[j + 1]; by = r2y[j + 1]; bz = r2z[j + 1];
    } else {                 // j == 4095 pad slot: dr2 = 0 -> term == 0 exactly
      bx = ax; by = ay; bz = az;
    }
    sA[tid] = make_float4(bx - ax, by - ay, bz - az, 0.5f * (bx + ax));
    sB[tid] = make_float2(0.5f * (by + ay), 0.5f * (bz + az));
  }
  __syncthreads();

  float acc = 0.0f;
  if (i < M) {
    float ax = r1x[i], ay = r1y[i], az = r1z[i];
    float bx = r1x[i + 1], by = r1y[i + 1], bz = r1z[i + 1];
    float d1x = bx - ax, d1y = by - ay, d1z = bz - az;
    float m1x = 0.5f * (bx + ax), m1y = 0.5f * (by + ay), m1z = 0.5f * (bz + az);

#pragma unroll 8
    for (int jj = 0; jj < JT; ++jj) {
      float4 A = sA[jj];
      float2 B = sB[jj];
      float dx = m1x - A.w;
      float dy = m1y - B.x;
      float dz = m1z - B.y;
      // cross(dr1, dr2)
      float cx = d1y * A.z - d1z * A.y;
      float cy = d1z * A.x - d1x * A.z;
      float cz = d1x * A.y - d1y * A.x;
      float num = cx * dx + cy * dy + cz * dz;
      float d2 = dx * dx + dy * dy + dz * dz + EPSF;
      float inv = rsqrtf(d2);
      inv = inv * (1.5f - 0.5f * d2 * inv * inv);  // one Newton step -> ~1 ulp
      acc += num * (inv * inv * inv);
    }
  }

  // wave (64-lane) shuffle reduction
  for (int off = 32; off > 0; off >>= 1)
    acc += __shfl_down(acc, off, 64);
  int lane = tid & 63, wid = tid >> 6;
  if (lane == 0) wsum[wid] = acc;
  __syncthreads();
  if (tid == 0) {
    float t = (wsum[0] + wsum[1]) + (wsum[2] + wsum[3]);
    atomicAdd(out, t * INV_4PI);
  }
}

extern "C" void kernel_launch(void* const* d_in, const int* in_sizes, int n_in,
                              void* d_out, int out_size, void* d_ws, size_t ws_size,
                              hipStream_t stream) {
  const float* bytes = (const float*)d_in[0];
  const int* idx = (const int*)d_in[1];
  float* out = (float*)d_out;
  float* ws = (float*)d_ws;

  precompute_kernel<<<dim3((N + 255) / 256), dim3(256), 0, stream>>>(bytes, idx, ws, out);
  gauss_pairs_kernel<<<dim3(16, 64), dim3(256), 0, stream>>>(ws, out);
}

// Round 2
// 66.007 us; speedup vs baseline: 1.1570x; 1.1570x over previous
//
#include <hip/hip_runtime.h>
#include <math.h>

#define N 4096
#define M 4095          // number of segments
#define EPSF 1e-9f
#define NT 1024         // single block, 16 waves, 1 CU
#define INV_4PI 0.07957747154594767f
#define TWO_PI 6.28318530717958647692f

// Key algebraic fact: q_bio = normalize(eye(4)[idx]) is an EXACT one-hot in
// fp32 (1.0f + 1e-9f == 1.0f), so r2[j] depends only on idx[j] in {0,1,2,3}.
// Hence (dr2_j, m2_j) depends only on the pair t=(idx[j],idx[j+1]) -- 16
// compile-time-constant types -- and the O(M^2) double sum collapses to
//   sum_i sum_{t} count_t * f(i, dr2_t, m2_t)
// Diagonal types (a==b) give dr2=0 -> num=0 -> exactly zero contribution.
__global__ __launch_bounds__(NT) void fused_gauss_kernel(
    const float* __restrict__ bytes, const int* __restrict__ idx,
    float* __restrict__ out) {
  __shared__ float r1x[N], r1y[N], r1z[N];   // 48 KB
  __shared__ int hist[16];
  __shared__ float wsum[NT / 64];

  const int tid = threadIdx.x;
  if (tid < 16) hist[tid] = 0;
  __syncthreads();

  // ---- Phase 1: r1 curve into LDS + histogram of (idx[j], idx[j+1]) ----
#pragma unroll
  for (int k = 0; k < N / NT; ++k) {
    int i = tid + k * NT;
    float b = bytes[i];
    float theta = (b / 255.0f) * TWO_PI;
    float s, c;
    sincosf(theta, &s, &c);
    float q1 = 0.5f * s, q2 = 0.3f * s, q3 = 0.2f * s;
    float n2 = c * c + q1 * q1 + q2 * q2 + q3 * q3 + EPSF;
    float inv = 1.0f / sqrtf(n2);
    r1x[i] = q1 * inv;
    r1y[i] = q2 * inv;
    r1z[i] = q3 * inv;
    if (i < M) {
      int a = idx[i], bb = idx[i + 1];
      if (a != bb) atomicAdd(&hist[a * 4 + bb], 1);
    }
  }
  __syncthreads();

  // Per-type constant geometry: basis vec p(k) = (k==1, k==2, k==3).
  // dr2_t = p(b)-p(a), m2_t = 0.5*(p(a)+p(b)).  All literals -> const-folded.
  const float PX[4] = {0.f, 1.f, 0.f, 0.f};
  const float PY[4] = {0.f, 0.f, 1.f, 0.f};
  const float PZ[4] = {0.f, 0.f, 0.f, 1.f};

  // Counts, loaded once (LDS broadcast), uniform across block.
  float cn[16];
#pragma unroll
  for (int t = 0; t < 16; ++t) cn[t] = (float)hist[t];

  // ---- Phase 2: sum over i of 12 constant types ----
  float acc = 0.0f;
#pragma unroll
  for (int k = 0; k < 4; ++k) {
    int i = tid + k * NT;
    if (i < M) {
      float ax = r1x[i], ay = r1y[i], az = r1z[i];
      float bx = r1x[i + 1], by = r1y[i + 1], bz = r1z[i + 1];
      float d1x = bx - ax, d1y = by - ay, d1z = bz - az;
      float m1x = 0.5f * (bx + ax), m1y = 0.5f * (by + ay), m1z = 0.5f * (bz + az);

#pragma unroll
      for (int t = 0; t < 16; ++t) {
        const int a = t >> 2, b = t & 3;
        if (a == b) continue;                       // dr2 = 0 -> exact zero
        const float ex = PX[b] - PX[a];             // dr2_t (constants)
        const float ey = PY[b] - PY[a];
        const float ez = PZ[b] - PZ[a];
        const float m2x = 0.5f * (PX[a] + PX[b]);   // m2_t (constants)
        const float m2y = 0.5f * (PY[a] + PY[b]);
        const float m2z = 0.5f * (PZ[a] + PZ[b]);

        float dx = m1x - m2x, dy = m1y - m2y, dz = m1z - m2z;
        // cross(d1, dr2_t) . diff  -- const-folds to ~2 live products
        float cx = d1y * ez - d1z * ey;
        float cy = d1z * ex - d1x * ez;
        float cz = d1x * ey - d1y * ex;
        float num = cx * dx + cy * dy + cz * dz;
        float d2 = dx * dx + dy * dy + dz * dz + EPSF;
        float inv = rsqrtf(d2);
        inv = inv * (1.5f - 0.5f * d2 * inv * inv); // Newton -> ~1 ulp
        acc += cn[t] * num * (inv * inv * inv);
      }
    }
  }

  // ---- Reduce: 64-lane shuffle, then across 16 waves ----
  for (int off = 32; off > 0; off >>= 1)
    acc += __shfl_down(acc, off, 64);
  int lane = tid & 63, wid = tid >> 6;
  if (lane == 0) wsum[wid] = acc;
  __syncthreads();
  if (tid == 0) {
    float t = 0.0f;
#pragma unroll
    for (int w = 0; w < NT / 64; ++w) t += wsum[w];
    out[0] = t * INV_4PI;
  }
}

extern "C" void kernel_launch(void* const* d_in, const int* in_sizes, int n_in,
                              void* d_out, int out_size, void* d_ws, size_t ws_size,
                              hipStream_t stream) {
  const float* bytes = (const float*)d_in[0];
  const int* idx = (const int*)d_in[1];
  float* out = (float*)d_out;

  fused_gauss_kernel<<<dim3(1), dim3(NT), 0, stream>>>(bytes, idx, out);
}

// Round 3
// 62.500 us; speedup vs baseline: 1.2219x; 1.0561x over previous
//
#include <hip/hip_runtime.h>
#include <math.h>

#define N 4096
#define M 4095          // number of segments
#define EPSF 1e-9f
#define NB 16           // blocks
#define BT 256          // threads per block
#define INV_4PI 0.07957747154594767f
#define TWO_PI 6.28318530717958647692f

// Algebraic collapse (verified R1, absmax 0.0): q_bio = normalize(eye(4)[idx])
// is an EXACT one-hot in fp32 (1.0f + 1e-9f == 1.0f), so (dr2_j, m2_j) depends
// only on the pair t=(idx[j],idx[j+1]) -- 16 compile-time types; diagonal
// types give dr2=0 -> exactly zero. O(M^2) -> O(M*12).
//
// R2 structure: no LDS curve staging, no single-block serialization. Each
// thread computes its own segment endpoints in registers; each block builds
// the full 16-bin histogram (duplicated -- 4095 LDS atomics is trivial);
// 16 blocks spread the work over 16 CUs; one atomicAdd per block into out
// (zeroed by a hipMemsetAsync node).

__device__ inline void r1_point(float b, float& x, float& y, float& z) {
  float theta = (b / 255.0f) * TWO_PI;
  float s, c;
  sincosf(theta, &s, &c);
  float q1 = 0.5f * s, q2 = 0.3f * s, q3 = 0.2f * s;
  float inv = 1.0f / sqrtf(c * c + q1 * q1 + q2 * q2 + q3 * q3 + EPSF);
  x = q1 * inv; y = q2 * inv; z = q3 * inv;
}

__global__ __launch_bounds__(BT) void gauss_kernel(
    const float* __restrict__ bytes, const int* __restrict__ idx,
    float* __restrict__ out) {
  __shared__ int hist[16];
  __shared__ float wsum[BT / 64];

  const int tid = threadIdx.x;
  if (tid < 16) hist[tid] = 0;
  __syncthreads();

  // Full (idx[j], idx[j+1]) histogram, duplicated in every block.
#pragma unroll
  for (int r = 0; r < 16; ++r) {        // covers j = 0..4095
    int j = tid + r * BT;
    if (j < M) {
      int a = idx[j], b = idx[j + 1];
      if (a != b) atomicAdd(&hist[a * 4 + b], 1);
    }
  }
  __syncthreads();

  // Basis point p(k) = (k==1, k==2, k==3); all type geometry const-folds.
  const float PX[4] = {0.f, 1.f, 0.f, 0.f};
  const float PY[4] = {0.f, 0.f, 1.f, 0.f};
  const float PZ[4] = {0.f, 0.f, 0.f, 1.f};

  float cn[16];
#pragma unroll
  for (int t = 0; t < 16; ++t) cn[t] = (float)hist[t];  // LDS broadcast

  float acc = 0.0f;
  int i = blockIdx.x * BT + tid;
  if (i < M) {
    float ax, ay, az, bx, by, bz;
    r1_point(bytes[i], ax, ay, az);
    r1_point(bytes[i + 1], bx, by, bz);
    float d1x = bx - ax, d1y = by - ay, d1z = bz - az;
    float m1x = 0.5f * (bx + ax), m1y = 0.5f * (by + ay), m1z = 0.5f * (bz + az);

#pragma unroll
    for (int t = 0; t < 16; ++t) {
      const int a = t >> 2, b = t & 3;
      if (a == b) continue;                     // dr2 = 0 -> exact zero
      const float ex = PX[b] - PX[a];           // dr2_t (constants)
      const float ey = PY[b] - PY[a];
      const float ez = PZ[b] - PZ[a];
      const float m2x = 0.5f * (PX[a] + PX[b]); // m2_t (constants)
      const float m2y = 0.5f * (PY[a] + PY[b]);
      const float m2z = 0.5f * (PZ[a] + PZ[b]);

      float dx = m1x - m2x, dy = m1y - m2y, dz = m1z - m2z;
      float cx = d1y * ez - d1z * ey;           // cross(d1, dr2_t), const-folded
      float cy = d1z * ex - d1x * ez;
      float cz = d1x * ey - d1y * ex;
      float num = cx * dx + cy * dy + cz * dz;
      float d2 = dx * dx + dy * dy + dz * dz + EPSF;
      float inv = rsqrtf(d2);
      inv = inv * (1.5f - 0.5f * d2 * inv * inv);  // Newton -> ~1 ulp
      acc += cn[t] * num * (inv * inv * inv);
    }
  }

  // 64-lane shuffle reduce, then across the 4 waves, one atomic per block.
  for (int off = 32; off > 0; off >>= 1)
    acc += __shfl_down(acc, off, 64);
  int lane = tid & 63, wid = tid >> 6;
  if (lane == 0) wsum[wid] = acc;
  __syncthreads();
  if (tid == 0) {
    float t = (wsum[0] + wsum[1]) + (wsum[2] + wsum[3]);
    atomicAdd(out, t * INV_4PI);
  }
}

extern "C" void kernel_launch(void* const* d_in, const int* in_sizes, int n_in,
                              void* d_out, int out_size, void* d_ws, size_t ws_size,
                              hipStream_t stream) {
  const float* bytes = (const float*)d_in[0];
  const int* idx = (const int*)d_in[1];
  float* out = (float*)d_out;

  hipMemsetAsync(out, 0, sizeof(float), stream);   // zero the accumulator (graph-capturable)
  gauss_kernel<<<dim3(NB), dim3(BT), 0, stream>>>(bytes, idx, out);
}

// Round 5
// 59.556 us; speedup vs baseline: 1.2823x; 1.0494x over previous
//
#include <hip/hip_runtime.h>
#include <math.h>

#define N 4096
#define M 4095          // number of segments
#define EPSF 1e-9f
#define NT 1024         // single block, 16 waves, 1 CU, 1 graph node
#define INV_4PI 0.07957747154594767f

// Algebra (verified R1/R2, absmax 0.0):
//  (1) q_bio = normalize(eye(4)[idx]) is an EXACT one-hot in fp32
//      (1.0f + 1e-9f == 1.0f), so (dr2_j, m2_j) depends only on the type
//      t=(idx[j], idx[j+1]) -- 16 compile-time constants; O(M^2) -> O(M*12).
//  (2) Swapping (a,b)->(b,a) flips dr2 but keeps m2, so the term is
//      antisymmetric: 12 types fold to 6 with signed weights
//      w_ab = cnt[a,b] - cnt[b,a].
//  (3) theta = b/255 * 2pi, and v_sin_f32/v_cos_f32 take REVOLUTIONS:
//      sin(theta) = v_sin(b/255), b/255 in [0,1) -- no range reduction.
__global__ __launch_bounds__(NT) void fused_gauss_kernel(
    const float* __restrict__ bytes, const int* __restrict__ idx,
    float* __restrict__ out) {
  __shared__ float r1x[N], r1y[N], r1z[N];   // 48 KB
  __shared__ int hist[16];
  __shared__ float wsum[NT / 64];

  const int tid = threadIdx.x;
  if (tid < 16) hist[tid] = 0;
  __syncthreads();

  // ---- Phase 1: r1 points into LDS (hardware sin/cos) + pair histogram ----
#pragma unroll
  for (int k = 0; k < N / NT; ++k) {
    int i = tid + k * NT;
    float rev = bytes[i] * (1.0f / 255.0f);          // revolutions in [0,1)
    float s = __builtin_amdgcn_sinf(rev);            // v_sin_f32: sin(2*pi*rev)
    float c = __builtin_amdgcn_cosf(rev);            // v_cos_f32
    float q1 = 0.5f * s, q2 = 0.3f * s, q3 = 0.2f * s;
    float n2 = c * c + q1 * q1 + q2 * q2 + q3 * q3 + EPSF;
    float inv = rsqrtf(n2);
    inv = inv * (1.5f - 0.5f * n2 * inv * inv);      // Newton -> ~1 ulp
    r1x[i] = q1 * inv;
    r1y[i] = q2 * inv;
    r1z[i] = q3 * inv;
    int a = idx[i];
    if (i < M) {
      int b = idx[i + 1];
      if (a != b) atomicAdd(&hist[a * 4 + b], 1);
    }
  }
  __syncthreads();

  // Signed weights for the 6 unordered types (a<b), uniform across block.
  const float PX[4] = {0.f, 1.f, 0.f, 0.f};
  const float PY[4] = {0.f, 0.f, 1.f, 0.f};
  const float PZ[4] = {0.f, 0.f, 0.f, 1.f};
  const int TA[6] = {0, 0, 0, 1, 1, 2};
  const int TB[6] = {1, 2, 3, 2, 3, 3};
  float w[6];
#pragma unroll
  for (int t = 0; t < 6; ++t)
    w[t] = (float)(hist[TA[t] * 4 + TB[t]] - hist[TB[t] * 4 + TA[t]]);

  // ---- Phase 2: sum over i of 6 signed constant types ----
  float acc = 0.0f;
#pragma unroll
  for (int k = 0; k < N / NT; ++k) {
    int i = tid + k * NT;
    if (i < M) {
      float ax = r1x[i], ay = r1y[i], az = r1z[i];
      float bx = r1x[i + 1], by = r1y[i + 1], bz = r1z[i + 1];
      float d1x = bx - ax, d1y = by - ay, d1z = bz - az;
      float m1x = 0.5f * (bx + ax), m1y = 0.5f * (by + ay), m1z = 0.5f * (bz + az);

#pragma unroll
      for (int t = 0; t < 6; ++t) {
        const int a = TA[t], b = TB[t];
        const float ex = PX[b] - PX[a];             // dr2_t (const-folded)
        const float ey = PY[b] - PY[a];
        const float ez = PZ[b] - PZ[a];
        const float m2x = 0.5f * (PX[a] + PX[b]);   // m2_t (const-folded)
        const float m2y = 0.5f * (PY[a] + PY[b]);
        const float m2z = 0.5f * (PZ[a] + PZ[b]);

        float dx = m1x - m2x, dy = m1y - m2y, dz = m1z - m2z;
        float cx = d1y * ez - d1z * ey;
        float cy = d1z * ex - d1x * ez;
        float cz = d1x * ey - d1y * ex;
        float num = cx * dx + cy * dy + cz * dz;
        float d2 = dx * dx + dy * dy + dz * dz + EPSF;
        float inv = rsqrtf(d2);
        inv = inv * (1.5f - 0.5f * d2 * inv * inv); // Newton -> ~1 ulp
        acc += w[t] * num * (inv * inv * inv);
      }
    }
  }

  // ---- Reduce: 64-lane shuffle, then across 16 waves; direct store ----
  for (int off = 32; off > 0; off >>= 1)
    acc += __shfl_down(acc, off, 64);
  int lane = tid & 63, wid = tid >> 6;
  if (lane == 0) wsum[wid] = acc;
  __syncthreads();
  if (tid == 0) {
    float t = 0.0f;
#pragma unroll
    for (int wv = 0; wv < NT / 64; ++wv) t += wsum[wv];
    out[0] = t * INV_4PI;
  }
}

extern "C" void kernel_launch(void* const* d_in, const int* in_sizes, int n_in,
                              void* d_out, int out_size, void* d_ws, size_t ws_size,
                              hipStream_t stream) {
  const float* bytes = (const float*)d_in[0];
  const int* idx = (const int*)d_in[1];
  float* out = (float*)d_out;

  fused_gauss_kernel<<<dim3(1), dim3(NT), 0, stream>>>(bytes, idx, out);
}